// Round 6
// baseline (7130.939 us; speedup 1.0000x reference)
//
#include <hip/hip_runtime.h>

// ============================================================================
// 2-layer LSTM (H=1024, B=128, T=256, future=64), persistent cooperative
// kernel, 256 WGs x 512 thr, 1 WG/CU, weights in LDS (MFMA B-frag order).
// R6: split-barrier pipeline. Two dependency loops with separate counters,
// flags, and per-XCD leaders: {h2(t-1) -> G2b} and {h1(t) -> G1/G2a}.
// Step order: waitF2 -> E1(t)+storeH1+arrive1 -> stream h2 + G2b MFMAs
// (h1 barrier round-trip hides behind this) -> waitF1 -> stream h1 + G1/G2a
// -> E2(t)+storeH2(+AR partial dot)+arrive2. H2 packed [hblk][row][hi4|lo4]
// so hi+lo come in ONE 16B load per lane. Full-line write-through stores,
// XCD-leader single-fence coherence (transport = relaxed agent atomics).
// ============================================================================

typedef _Float16 f16;
typedef _Float16 f16x8 __attribute__((ext_vector_type(8)));
typedef _Float16 f16x4 __attribute__((ext_vector_type(4)));
typedef float    f32x4 __attribute__((ext_vector_type(4)));
typedef int      i32x4 __attribute__((ext_vector_type(4)));
typedef unsigned int   u32;
typedef unsigned short u16;

#define NB   256
#define WGS  512
#define HS   1024
#define BS   128
#define TS   256
#define TTS  320
#define KST  32      // 1024 / 32
#define P1STR 131072 // f16 elems per H1 parity plane: 256*128*4
#define P2STR 262144 // f16 elems per H2 parity plane: 256*128*8 (hi4|lo4)

// workspace byte offsets
#define OFF_H1    0u         // f16 [2][256][128][4]        524288 B
#define OFF_H2    524288u    // f16 [2][256][128][8]       1048576 B
#define OFF_CNT1  1572864u   // int [64 slots x 1024-int]   262144 B
#define OFF_CNT2  1835008u   // int [64 slots x 1024-int]   262144 B
#define OFF_FLAG  2097152u   // int [8 xcd x 2048-int]       65536 B
#define OFF_XREG  2162688u   // int [8 xcd x 16]               512 B
#define OFF_ACC   2163200u   // float [65][128]              33280 B
#define WS_END    2196480u

#define NSLOT       64
#define SLOT_TGT    4        // 256 blocks / 64 slots
#define SLOT_STRIDE 1024     // ints: 4KB between slots

// LDS byte offsets
#define LDS_G1    131072     // float[128][16]
#define LDS_G2    139264     // float[128][16]
#define LDS_XF    147456     // float[128]
#define LDS_PRM   147968     // wih1[16], b1[16], b2[16], blin
#define LDS_MISC  148224     // int[2]: xcd, leader-kind
#define LDS_SH1   148352     // f16[512]  stage h1  [row][4]
#define LDS_SH2   149376     // f16[1024] stage h2  [row][hi4|lo4]
#define LDS_TOTAL 151552

__device__ __forceinline__ float sigm(float x){ return 1.0f/(1.0f + __expf(-x)); }

__device__ __forceinline__ void wt_store(u32* p, u32 v) {
  __hip_atomic_store(p, v, __ATOMIC_RELAXED, __HIP_MEMORY_SCOPE_AGENT);
}

// full-line write-through 16B store (to coherence point)
__device__ __forceinline__ void st16_wt(f16* addr, f16x8 v) {
  i32x4 d = __builtin_bit_cast(i32x4, v);
  asm volatile("global_store_dwordx4 %0, %1, off sc0 sc1"
               :: "v"(addr), "v"(d) : "memory");
}

// arrival: own stores/atomics drained per wave, all waves synced, one add
__device__ __forceinline__ void bar_arrive(int* cnt, int t, int blk) {
  asm volatile("s_waitcnt vmcnt(0)" ::: "memory");
  __syncthreads();
  if (threadIdx.x == 0)
    __hip_atomic_fetch_add(cnt + (blk & (NSLOT-1)) * SLOT_STRIDE + t, 1,
                           __ATOMIC_RELAXED, __HIP_MEMORY_SCOPE_AGENT);
}

// leader: poll 64 slots -> ONE acquire fence (this XCD's L2 inv) -> publish
// monotone flag. non-leader: poll flag relaxed (no fence).
__device__ __forceinline__ void bar_wait(const int* cnt, int t, int* flagaddr,
                                         bool lead) {
  if (lead) {
    if (threadIdx.x < NSLOT) {
      const int* p = cnt + threadIdx.x * SLOT_STRIDE + t;
      while (__hip_atomic_load(p, __ATOMIC_RELAXED, __HIP_MEMORY_SCOPE_AGENT) < SLOT_TGT)
        __builtin_amdgcn_s_sleep(1);
    }
    if ((threadIdx.x >> 6) == 0) {
      __builtin_amdgcn_fence(__ATOMIC_ACQUIRE, "agent");
      asm volatile("s_waitcnt vmcnt(0)" ::: "memory");
    }
    __syncthreads();
    if (threadIdx.x == 0)
      __hip_atomic_store(flagaddr, t + 1, __ATOMIC_RELAXED, __HIP_MEMORY_SCOPE_AGENT);
  } else {
    if (threadIdx.x == 0) {
      while (__hip_atomic_load(flagaddr, __ATOMIC_RELAXED, __HIP_MEMORY_SCOPE_AGENT) < t + 1)
        __builtin_amdgcn_s_sleep(1);
    }
    __syncthreads();
  }
}

__global__ void init_ws_kernel(char* ws){
  // zero H2 parity-1 plane + cnt1 + cnt2 + flags + xreg + acc (contiguous)
  const size_t n = (WS_END - 1048576u) / 16u;
  float4* r = (float4*)(ws + 1048576u);
  float4 z = make_float4(0.f, 0.f, 0.f, 0.f);
  size_t stride = (size_t)gridDim.x * blockDim.x;
  for (size_t i = blockIdx.x*(size_t)blockDim.x + threadIdx.x; i < n; i += stride) r[i] = z;
  __builtin_amdgcn_fence(__ATOMIC_RELEASE, "agent");
}

__global__ void __launch_bounds__(WGS, 2)
lstm_coop(const float* __restrict__ xg,
          const float* __restrict__ Wih1, const float* __restrict__ Whh1,
          const float* __restrict__ bih1, const float* __restrict__ bhh1,
          const float* __restrict__ Wih2, const float* __restrict__ Whh2,
          const float* __restrict__ bih2, const float* __restrict__ bhh2,
          const float* __restrict__ Wlin, const float* __restrict__ blin,
          float* __restrict__ outp, char* __restrict__ ws)
{
  extern __shared__ char smem[];
  f16*   Wlds = (f16*)smem;                    // [(tile*32+k0)*64+lane]*8 f16
  float* g1s  = (float*)(smem + LDS_G1);
  float* g2s  = (float*)(smem + LDS_G2);
  float* xfd  = (float*)(smem + LDS_XF);
  float* prm  = (float*)(smem + LDS_PRM);
  int*   miscl= (int*)(smem + LDS_MISC);
  f16*   sh1  = (f16*)(smem + LDS_SH1);
  f16*   sh2  = (f16*)(smem + LDS_SH2);

  f16* H1  = (f16*)(ws + OFF_H1);
  f16* H2  = (f16*)(ws + OFF_H2);
  int* cnt1 = (int*)(ws + OFF_CNT1);
  int* cnt2 = (int*)(ws + OFF_CNT2);
  int* flags= (int*)(ws + OFF_FLAG);
  float* accs = (float*)(ws + OFF_ACC);

  const int tid = threadIdx.x;
  const int blk = blockIdx.x;

  // ---- XCD self-id + two leaders per XCD (rank0 -> h2 flag, rank1 -> h1) ----
  int xcd_raw;
  asm("s_getreg_b32 %0, hwreg(HW_REG_XCC_ID)" : "=s"(xcd_raw));
  if (tid == 0) {
    int x = xcd_raw & 7;
    int rank = __hip_atomic_fetch_add((int*)(ws + OFF_XREG) + x*16, 1,
                                      __ATOMIC_RELAXED, __HIP_MEMORY_SCOPE_AGENT);
    miscl[0] = x;
    miscl[1] = (rank == 0) ? 2 : (rank == 1) ? 1 : 0;
  }

  // ---- prologue: pack weights into LDS in MFMA B-frag order ----
  // tiles: 0=G1(Whh1) 1=G2a(Wih2) 2=G2b(Whh2) 3=OUT(Wlin col0, rest 0)
  for (int item = tid; item < 4*KST*64; item += WGS) {
    int tile = item >> 11;
    int rem  = item & 2047;
    int k0   = rem >> 6;
    int lane = rem & 63;
    int n    = lane & 15;
    int kbase = k0*32 + (lane>>4)*8;
    f16x8 pk;
    if (tile < 3) {
      const float* Wsrc = (tile==0) ? Whh1 : (tile==1) ? Wih2 : Whh2;
      const float* p = Wsrc + (size_t)((n>>2)*1024 + blk*4 + (n&3))*HS + kbase;
      #pragma unroll
      for (int j=0;j<8;j++) pk[j] = (f16)p[j];
    } else {
      #pragma unroll
      for (int j=0;j<8;j++) pk[j] = (n==0) ? (f16)Wlin[kbase+j] : (f16)0.0f;
    }
    *(f16x8*)(Wlds + (size_t)item*8) = pk;
  }
  if (tid < 16) {
    int row = (tid>>2)*1024 + blk*4 + (tid&3);
    prm[tid]      = Wih1[row];
    prm[16 + tid] = bih1[row] + bhh1[row];
    prm[32 + tid] = bih2[row] + bhh2[row];
  }
  if (tid == 16) prm[48] = blin[0];

  const int erow = tid >> 2;        // elementwise: batch row
  const int eu   = tid & 3;         // unit within CU
  const float wlin_c = Wlin[blk*4 + eu];
  float c1 = 0.f, c2 = 0.f;
  __syncthreads();

  const int  myxcd = miscl[0];
  const int  lkind = miscl[1];      // 2 = h2-flag leader, 1 = h1-flag leader
  int* flag2 = flags + myxcd * 2048;        // monotone t+1 (h2 ready)
  int* flag1 = flags + myxcd * 2048 + 64;   // monotone t+1 (h1 ready)

  // MFMA identity
  const int wv    = tid >> 6;
  const int lane  = tid & 63;
  const int n15   = lane & 15;
  const int mrow  = wv*16 + n15;          // A-frag row (batch)
  const int kc    = (lane>>4)*8;          // A/B-frag k sub-offset
  const int rbase = wv*16 + (lane>>4)*4;  // C/D row base
  const f16x8* WB = (const f16x8*)Wlds;
  const int abase1 = mrow*4 + (kc>>2)*512;            // H1 frag base (f16)
  const int abase2 = mrow*8 + (kc>>2)*1024;           // H2 frag base (f16)

  // prologue arrival: h2(-1) zero plane is visible (init kernel + fence)
  bar_arrive(cnt2, 0, blk);

  for (int t = 0; t < TTS; ++t) {
    // ---- [A] wait h2(t-1) visible (also: AR sums(t-1) complete) ----
    bar_wait(cnt2, t, flag2, lkind == 2);

    // ---- [A2] E1(t): h1(t); store; arrive cnt1[t]. AR: xfd from sums ----
    if (t >= TS) {
      float myo = 0.f;
      if (tid < BS) {
        myo = __hip_atomic_load(accs + (t-TS)*BS + tid,
                                __ATOMIC_RELAXED, __HIP_MEMORY_SCOPE_AGENT) + prm[48];
        xfd[tid] = myo;
        if (blk == 0) wt_store((u32*)&outp[tid*TTS + (t-1)],
                               __builtin_bit_cast(u32, myo));
      }
      __syncthreads();
    }
    {
      float h1v;
      if (t == 0) {
        float xv = xg[erow*TS + 0];
        float gi = xv*prm[0*4+eu] + prm[16 + 0*4+eu];
        float gg = xv*prm[2*4+eu] + prm[16 + 2*4+eu];
        float go = xv*prm[3*4+eu] + prm[16 + 3*4+eu];
        c1 = sigm(gi)*tanhf(gg);
        h1v = sigm(go)*tanhf(c1);
      } else {
        float xv = (t < TS) ? xg[erow*TS + t] : xfd[erow];
        float gi = g1s[erow*16 + 0*4+eu] + xv*prm[0*4+eu];
        float gf = g1s[erow*16 + 1*4+eu] + xv*prm[1*4+eu];
        float gg = g1s[erow*16 + 2*4+eu] + xv*prm[2*4+eu];
        float go = g1s[erow*16 + 3*4+eu] + xv*prm[3*4+eu];
        c1 = sigm(gf)*c1 + sigm(gi)*tanhf(gg);
        h1v = sigm(go)*tanhf(c1);
      }
      sh1[tid] = (f16)h1v;   // [row][4] layout == tid
    }
    __syncthreads();
    if (wv == 0)
      st16_wt(H1 + (size_t)(t&1)*P1STR + blk*512 + lane*8,
              *(const f16x8*)(sh1 + lane*8));
    bar_arrive(cnt1, t, blk);

    // ---- [B] stream h2(t-1), G2b + accO (h1 barrier hides behind this) ----
    const f16* A2 = H2 + (size_t)((t+1)&1)*P2STR + abase2;
    f32x4 acc2b = {0.f,0.f,0.f,0.f};
    f32x4 accO  = {0.f,0.f,0.f,0.f};
    #pragma unroll 8
    for (int k0 = 0; k0 < KST; ++k0) {
      f16x8 L0 = *(const f16x8*)(A2 + k0*8192);
      f16x8 L1 = *(const f16x8*)(A2 + k0*8192 + 1024);
      f16x8 a2h = __builtin_shufflevector(L0, L1, 0,1,2,3, 8,9,10,11);
      f16x8 a2l = __builtin_shufflevector(L0, L1, 4,5,6,7, 12,13,14,15);
      f16x8 b2 = WB[(2*KST + k0)*64 + lane];
      f16x8 b3 = WB[(3*KST + k0)*64 + lane];
      acc2b = __builtin_amdgcn_mfma_f32_16x16x32_f16(a2h, b2, acc2b, 0,0,0);
      acc2b = __builtin_amdgcn_mfma_f32_16x16x32_f16(a2l, b2, acc2b, 0,0,0);
      accO  = __builtin_amdgcn_mfma_f32_16x16x32_f16(a2h, b3, accO,  0,0,0);
    }
    if (n15 == 0 && blk == 0 && t >= 1 && t <= TS-1) {
      #pragma unroll
      for (int r = 0; r < 4; ++r)
        wt_store((u32*)&outp[(rbase+r)*TTS + (t-1)],
                 __builtin_bit_cast(u32, accO[r] + prm[48]));
    }

    // ---- [C] wait h1(t) visible ----
    bar_wait(cnt1, t, flag1, lkind == 1);

    // ---- [D] stream h1(t), G1 + G2a; stage gates ----
    const f16* A1 = H1 + (size_t)(t&1)*P1STR + abase1;
    f32x4 acc1  = {0.f,0.f,0.f,0.f};
    f32x4 acc2a = {0.f,0.f,0.f,0.f};
    #pragma unroll 8
    for (int k0 = 0; k0 < KST; ++k0) {
      f16x4 a1l = *(const f16x4*)(A1 + k0*4096);
      f16x4 a1h = *(const f16x4*)(A1 + k0*4096 + 512);
      f16x8 a1  = __builtin_shufflevector(a1l, a1h, 0,1,2,3,4,5,6,7);
      f16x8 b0 = WB[(0*KST + k0)*64 + lane];
      f16x8 b1 = WB[(1*KST + k0)*64 + lane];
      acc1  = __builtin_amdgcn_mfma_f32_16x16x32_f16(a1, b0, acc1,  0,0,0);
      acc2a = __builtin_amdgcn_mfma_f32_16x16x32_f16(a1, b1, acc2a, 0,0,0);
    }
    #pragma unroll
    for (int r = 0; r < 4; ++r) {
      int grow = rbase + r;
      g1s[grow*16 + n15] = acc1[r]  + prm[16 + n15];
      g2s[grow*16 + n15] = acc2a[r] + acc2b[r] + prm[32 + n15];
    }
    __syncthreads();

    // ---- [E] E2(t): h2(t); stage hi|lo; AR partial dot; store ----
    {
      float gi = g2s[erow*16 + 0*4+eu];
      float gf = g2s[erow*16 + 1*4+eu];
      float gg = g2s[erow*16 + 2*4+eu];
      float go = g2s[erow*16 + 3*4+eu];
      c2 = sigm(gf)*c2 + sigm(gi)*tanhf(gg);
      float h2v = sigm(go)*tanhf(c2);
      f16 hh = (f16)h2v;
      sh2[erow*8 + eu]     = hh;
      sh2[erow*8 + 4 + eu] = (f16)(h2v - (float)hh);
      if (t >= TS-1) {
        float p = h2v * wlin_c;
        p += __shfl_xor(p, 1);
        p += __shfl_xor(p, 2);
        if (eu == 0)
          __hip_atomic_fetch_add(accs + (t-(TS-1))*BS + erow, p,
                                 __ATOMIC_RELAXED, __HIP_MEMORY_SCOPE_AGENT);
      }
    }
    __syncthreads();
    if (wv == 1)
      st16_wt(H2 + (size_t)(t&1)*P2STR + blk*1024 + lane*8,
              *(const f16x8*)(sh2 + lane*8));
    else if (wv == 2)
      st16_wt(H2 + (size_t)(t&1)*P2STR + blk*1024 + 512 + lane*8,
              *(const f16x8*)(sh2 + 512 + lane*8));

    // ---- [F] arrive h2(t) + AR sums(t) ----
    bar_arrive(cnt2, t+1, blk);
  }

  // ---- epilogue: out(TTS-1) from sums (blk0 only; atomic loads, no fence) --
  if (blk == 0) {
    if (tid < NSLOT) {
      const int* p = cnt2 + tid * SLOT_STRIDE + TTS;
      while (__hip_atomic_load(p, __ATOMIC_RELAXED, __HIP_MEMORY_SCOPE_AGENT) < SLOT_TGT)
        __builtin_amdgcn_s_sleep(1);
    }
    __syncthreads();
    if (tid < BS) {
      float v = __hip_atomic_load(accs + (TTS-TS)*BS + tid,
                                  __ATOMIC_RELAXED, __HIP_MEMORY_SCOPE_AGENT) + prm[48];
      wt_store((u32*)&outp[tid*TTS + (TTS-1)], __builtin_bit_cast(u32, v));
    }
  }
}

extern "C" void kernel_launch(void* const* d_in, const int* in_sizes, int n_in,
                              void* d_out, int out_size, void* d_ws, size_t ws_size,
                              hipStream_t stream) {
  const float* xg   = (const float*)d_in[0];
  const float* Wih1 = (const float*)d_in[1];
  const float* Whh1 = (const float*)d_in[2];
  const float* bih1 = (const float*)d_in[3];
  const float* bhh1 = (const float*)d_in[4];
  const float* Wih2 = (const float*)d_in[5];
  const float* Whh2 = (const float*)d_in[6];
  const float* bih2 = (const float*)d_in[7];
  const float* bhh2 = (const float*)d_in[8];
  const float* Wlin = (const float*)d_in[9];
  const float* blin = (const float*)d_in[10];
  float* outp = (float*)d_out;
  char* ws = (char*)d_ws;

  init_ws_kernel<<<dim3(128), dim3(256), 0, stream>>>(ws);

  (void)hipFuncSetAttribute((const void*)lstm_coop,
                            hipFuncAttributeMaxDynamicSharedMemorySize, LDS_TOTAL);

  void* args[] = { (void*)&xg, (void*)&Wih1, (void*)&Whh1, (void*)&bih1, (void*)&bhh1,
                   (void*)&Wih2, (void*)&Whh2, (void*)&bih2, (void*)&bhh2,
                   (void*)&Wlin, (void*)&blin, (void*)&outp, (void*)&ws };
  hipError_t err = hipLaunchCooperativeKernel((const void*)lstm_coop,
                                              dim3(NB), dim3(WGS), args, LDS_TOTAL, stream);
  if (err != hipSuccess) {
    lstm_coop<<<dim3(NB), dim3(WGS), LDS_TOTAL, stream>>>(
        xg, Wih1, Whh1, bih1, bhh1, Wih2, Whh2, bih2, bhh2, Wlin, blin, outp, ws);
  }
}

// Round 7
// 5544.443 us; speedup vs baseline: 1.2861x; 1.2861x over previous
//
#include <hip/hip_runtime.h>

// ============================================================================
// 2-layer LSTM (H=1024, B=128, T=256, future=64), persistent cooperative
// kernel, 256 WGs x 512 thr, 1 WG/CU, weights in LDS (MFMA B-frag order).
// R7: single-rendezvous pipeline. E1(t) hoisted BEFORE the barrier (needs
// only block-local g1s(t-1)+x); wv0 stores h1+arrives, wv1 stores h2+arrives
// (wave-local vmcnt acks), wv7 polls; ONE leader fence per XCD per step gates
// both {h1(t), h2(t-1)}; fused 4-load/5-MFMA k-loop streams h1+h2 together.
// AR sums read fence-free (atomic loads) gated by a direct cnt2 poll.
// ============================================================================

typedef _Float16 f16;
typedef _Float16 f16x8 __attribute__((ext_vector_type(8)));
typedef _Float16 f16x4 __attribute__((ext_vector_type(4)));
typedef float    f32x4 __attribute__((ext_vector_type(4)));
typedef int      i32x4 __attribute__((ext_vector_type(4)));
typedef unsigned int   u32;
typedef unsigned short u16;

#define NB   256
#define WGS  512
#define HS   1024
#define BS   128
#define TS   256
#define TTS  320
#define KST  32      // 1024 / 32
#define P1STR 131072 // f16 per H1 plane: 256*128*4
#define P2STR 262144 // f16 per H2 plane: 256*128*8 (hi4|lo4)

// workspace byte offsets
#define OFF_H1    0u         // f16 [2][256][128][4]        524288 B
#define OFF_H2    524288u    // f16 [2][256][128][8]       1048576 B
#define OFF_CNT1  1572864u   // int [64 slots x 1024-int]   262144 B
#define OFF_CNT2  1835008u   // int [64 slots x 1024-int]   262144 B
#define OFF_FLAG  2097152u   // int [8 xcd x 2048-int]       65536 B
#define OFF_XREG  2162688u   // int [8 xcd x 16]               512 B
#define OFF_ACC   2163200u   // float [65][128]              33280 B
#define WS_END    2196480u

#define NSLOT       64
#define SLOT_TGT    4        // 256 blocks / 64 slots
#define SLOT_STRIDE 1024     // ints: 4KB between slots

// LDS byte offsets
#define LDS_G1    131072     // float[128][16]
#define LDS_G2    139264     // float[128][16]
#define LDS_XF    147456     // float[128]
#define LDS_PRM   147968     // wih1[16], b1[16], b2[16], blin
#define LDS_MISC  148224     // int[2]: xcd, leader
#define LDS_SH1   148352     // f16[512]  stage h1  [row][4]
#define LDS_SH2   149376     // f16[1024] stage h2  [row][hi4|lo4]
#define LDS_TOTAL 151552

__device__ __forceinline__ float sigm(float x){ return 1.0f/(1.0f + __expf(-x)); }

__device__ __forceinline__ void wt_store(u32* p, u32 v) {
  __hip_atomic_store(p, v, __ATOMIC_RELAXED, __HIP_MEMORY_SCOPE_AGENT);
}

// full-line write-through 16B store (to coherence point)
__device__ __forceinline__ void st16_wt(f16* addr, f16x8 v) {
  i32x4 d = __builtin_bit_cast(i32x4, v);
  asm volatile("global_store_dwordx4 %0, %1, off sc0 sc1"
               :: "v"(addr), "v"(d) : "memory");
}

// per-lane slot poll (call from wv7: lane l polls slot l)
__device__ __forceinline__ void poll_slots(const int* cnt, int t) {
  const int* p = cnt + (threadIdx.x & 63) * SLOT_STRIDE + t;
  while (__hip_atomic_load(p, __ATOMIC_RELAXED, __HIP_MEMORY_SCOPE_AGENT) < SLOT_TGT)
    __builtin_amdgcn_s_sleep(1);
}

__global__ void init_ws_kernel(char* ws){
  // zero cnt1 + cnt2 + flags + xreg + acc (contiguous)
  const size_t n = (WS_END - OFF_CNT1) / 16u;
  float4* r = (float4*)(ws + OFF_CNT1);
  float4 z = make_float4(0.f, 0.f, 0.f, 0.f);
  size_t stride = (size_t)gridDim.x * blockDim.x;
  for (size_t i = blockIdx.x*(size_t)blockDim.x + threadIdx.x; i < n; i += stride) r[i] = z;
  __builtin_amdgcn_fence(__ATOMIC_RELEASE, "agent");
}

__global__ void __launch_bounds__(WGS, 2)
lstm_coop(const float* __restrict__ xg,
          const float* __restrict__ Wih1, const float* __restrict__ Whh1,
          const float* __restrict__ bih1, const float* __restrict__ bhh1,
          const float* __restrict__ Wih2, const float* __restrict__ Whh2,
          const float* __restrict__ bih2, const float* __restrict__ bhh2,
          const float* __restrict__ Wlin, const float* __restrict__ blin,
          float* __restrict__ outp, char* __restrict__ ws)
{
  extern __shared__ char smem[];
  f16*   Wlds = (f16*)smem;                    // [(tile*32+k0)*64+lane]*8 f16
  float* g1s  = (float*)(smem + LDS_G1);
  float* g2s  = (float*)(smem + LDS_G2);
  float* xfd  = (float*)(smem + LDS_XF);
  float* prm  = (float*)(smem + LDS_PRM);
  int*   miscl= (int*)(smem + LDS_MISC);
  f16*   sh1  = (f16*)(smem + LDS_SH1);
  f16*   sh2  = (f16*)(smem + LDS_SH2);

  f16* H1  = (f16*)(ws + OFF_H1);
  f16* H2  = (f16*)(ws + OFF_H2);
  int* cnt1 = (int*)(ws + OFF_CNT1);
  int* cnt2 = (int*)(ws + OFF_CNT2);
  int* flags= (int*)(ws + OFF_FLAG);
  float* accs = (float*)(ws + OFF_ACC);

  const int tid = threadIdx.x;
  const int blk = blockIdx.x;

  // ---- XCD self-id + leader election (rank0 of each XCC_ID group) ----
  int xcd_raw;
  asm("s_getreg_b32 %0, hwreg(HW_REG_XCC_ID)" : "=s"(xcd_raw));
  if (tid == 0) {
    int x = xcd_raw & 7;
    int rank = __hip_atomic_fetch_add((int*)(ws + OFF_XREG) + x*16, 1,
                                      __ATOMIC_RELAXED, __HIP_MEMORY_SCOPE_AGENT);
    miscl[0] = x;
    miscl[1] = (rank == 0) ? 1 : 0;
  }

  // ---- prologue: pack weights into LDS in MFMA B-frag order ----
  // tiles: 0=G1(Whh1) 1=G2a(Wih2) 2=G2b(Whh2) 3=OUT(Wlin col0, rest 0)
  for (int item = tid; item < 4*KST*64; item += WGS) {
    int tile = item >> 11;
    int rem  = item & 2047;
    int k0   = rem >> 6;
    int lane = rem & 63;
    int n    = lane & 15;
    int kbase = k0*32 + (lane>>4)*8;
    f16x8 pk;
    if (tile < 3) {
      const float* Wsrc = (tile==0) ? Whh1 : (tile==1) ? Wih2 : Whh2;
      const float* p = Wsrc + (size_t)((n>>2)*1024 + blk*4 + (n&3))*HS + kbase;
      #pragma unroll
      for (int j=0;j<8;j++) pk[j] = (f16)p[j];
    } else {
      #pragma unroll
      for (int j=0;j<8;j++) pk[j] = (n==0) ? (f16)Wlin[kbase+j] : (f16)0.0f;
    }
    *(f16x8*)(Wlds + (size_t)item*8) = pk;
  }
  if (tid < 16) {
    int row = (tid>>2)*1024 + blk*4 + (tid&3);
    prm[tid]      = Wih1[row];
    prm[16 + tid] = bih1[row] + bhh1[row];
    prm[32 + tid] = bih2[row] + bhh2[row];
  }
  if (tid == 16) prm[48] = blin[0];

  const int erow = tid >> 2;        // elementwise: batch row
  const int eu   = tid & 3;         // unit within CU
  const float wlin_c = Wlin[blk*4 + eu];
  float c1 = 0.f, c2 = 0.f;
  __syncthreads();

  const int  myxcd  = miscl[0];
  const bool leader = miscl[1] != 0;
  int* flag = flags + myxcd * 2048;         // monotone t+1

  // MFMA identity
  const int wv    = tid >> 6;
  const int lane  = tid & 63;
  const int n15   = lane & 15;
  const int mrow  = wv*16 + n15;          // A-frag row (batch)
  const int kc    = (lane>>4)*8;          // A/B-frag k sub-offset
  const int rbase = wv*16 + (lane>>4)*4;  // C/D row base
  const f16x8* WB = (const f16x8*)Wlds;
  const int abase1 = mrow*4 + (kc>>2)*512;   // H1 frag base (f16)
  const int abase2 = mrow*8 + (kc>>2)*1024;  // H2 frag base (f16)

  for (int t = 0; t < TTS; ++t) {
    const int p1 = t & 1;          // h1(t) plane (written this step)
    const int p2 = (t + 1) & 1;    // h2(t-1) plane (read this step)

    // ---- [AR pre] out(t-1) from sums; fence-free (atomic loads) ----
    if (t >= TS) {
      if (wv == 7) poll_slots(cnt2, t);
      __syncthreads();
      if (tid < BS) {
        float v = __hip_atomic_load(accs + (t-TS)*BS + tid,
                                    __ATOMIC_RELAXED, __HIP_MEMORY_SCOPE_AGENT) + prm[48];
        xfd[tid] = v;
        if (blk == ((t-1) & 255))
          wt_store((u32*)&outp[tid*TTS + (t-1)], __builtin_bit_cast(u32, v));
      }
      __syncthreads();
    }

    // ---- [E1(t)] block-local: g1s(t-1) + x(t) (or xfd) ----
    {
      float h1v;
      if (t == 0) {
        float xv = xg[erow*TS + 0];
        float gi = xv*prm[0*4+eu] + prm[16 + 0*4+eu];
        float gg = xv*prm[2*4+eu] + prm[16 + 2*4+eu];
        float go = xv*prm[3*4+eu] + prm[16 + 3*4+eu];
        c1 = sigm(gi)*tanhf(gg);
        h1v = sigm(go)*tanhf(c1);
      } else {
        float xv = (t < TS) ? xg[erow*TS + t] : xfd[erow];
        float gi = g1s[erow*16 + 0*4+eu] + xv*prm[0*4+eu];
        float gf = g1s[erow*16 + 1*4+eu] + xv*prm[1*4+eu];
        float gg = g1s[erow*16 + 2*4+eu] + xv*prm[2*4+eu];
        float go = g1s[erow*16 + 3*4+eu] + xv*prm[3*4+eu];
        c1 = sigm(gf)*c1 + sigm(gi)*tanhf(gg);
        h1v = sigm(go)*tanhf(c1);
      }
      sh1[tid] = (f16)h1v;
    }
    __syncthreads();

    // ---- [wv0] store h1(t) + arrive1 (wave-local ack) ----
    if (wv == 0) {
      st16_wt(H1 + (size_t)p1*P1STR + blk*512 + lane*8,
              *(const f16x8*)(sh1 + lane*8));
      asm volatile("s_waitcnt vmcnt(0)" ::: "memory");
      if (lane == 0)
        __hip_atomic_fetch_add(cnt1 + (blk & (NSLOT-1))*SLOT_STRIDE + t, 1,
                               __ATOMIC_RELAXED, __HIP_MEMORY_SCOPE_AGENT);
    }

    // ---- [rendezvous] ONE leader fence per XCD gates h1(t)+h2(t-1) ----
    if (wv == 7) {
      if (leader) {
        if (t >= 1) poll_slots(cnt2, t);
        poll_slots(cnt1, t);
        __builtin_amdgcn_fence(__ATOMIC_ACQUIRE, "agent");   // one L1+L2 inv
        asm volatile("s_waitcnt vmcnt(0)" ::: "memory");
        if (lane == 0)
          __hip_atomic_store(flag, t + 1, __ATOMIC_RELAXED, __HIP_MEMORY_SCOPE_AGENT);
      } else {
        if (lane == 0) {
          while (__hip_atomic_load(flag, __ATOMIC_RELAXED, __HIP_MEMORY_SCOPE_AGENT) < t + 1)
            __builtin_amdgcn_s_sleep(1);
        }
      }
    }
    __syncthreads();

    // ---- [stream] fused h1+h2 k-loop: G1, G2a, G2b(hi,lo), accO ----
    const f16* A1 = H1 + (size_t)p1*P1STR + abase1;
    const f16* A2 = H2 + (size_t)p2*P2STR + abase2;
    f32x4 acc1  = {0.f,0.f,0.f,0.f};
    f32x4 acc2a = {0.f,0.f,0.f,0.f};
    f32x4 acc2b = {0.f,0.f,0.f,0.f};
    f32x4 accO  = {0.f,0.f,0.f,0.f};
    if (t == 0) {   // h2(-1) == 0: h1-only
      #pragma unroll 8
      for (int k0 = 0; k0 < KST; ++k0) {
        f16x4 a1l = *(const f16x4*)(A1 + k0*4096);
        f16x4 a1h = *(const f16x4*)(A1 + k0*4096 + 512);
        f16x8 a1  = __builtin_shufflevector(a1l, a1h, 0,1,2,3,4,5,6,7);
        f16x8 b0 = WB[(0*KST + k0)*64 + lane];
        f16x8 b1 = WB[(1*KST + k0)*64 + lane];
        acc1  = __builtin_amdgcn_mfma_f32_16x16x32_f16(a1, b0, acc1,  0,0,0);
        acc2a = __builtin_amdgcn_mfma_f32_16x16x32_f16(a1, b1, acc2a, 0,0,0);
      }
    } else {
      #pragma unroll 8
      for (int k0 = 0; k0 < KST; ++k0) {
        f16x4 a1l = *(const f16x4*)(A1 + k0*4096);
        f16x4 a1h = *(const f16x4*)(A1 + k0*4096 + 512);
        f16x8 L0  = *(const f16x8*)(A2 + k0*8192);
        f16x8 L1  = *(const f16x8*)(A2 + k0*8192 + 1024);
        f16x8 a1  = __builtin_shufflevector(a1l, a1h, 0,1,2,3,4,5,6,7);
        f16x8 a2h = __builtin_shufflevector(L0, L1, 0,1,2,3, 8,9,10,11);
        f16x8 a2l = __builtin_shufflevector(L0, L1, 4,5,6,7, 12,13,14,15);
        f16x8 b0 = WB[(0*KST + k0)*64 + lane];
        f16x8 b1 = WB[(1*KST + k0)*64 + lane];
        f16x8 b2 = WB[(2*KST + k0)*64 + lane];
        f16x8 b3 = WB[(3*KST + k0)*64 + lane];
        acc1  = __builtin_amdgcn_mfma_f32_16x16x32_f16(a1,  b0, acc1,  0,0,0);
        acc2a = __builtin_amdgcn_mfma_f32_16x16x32_f16(a1,  b1, acc2a, 0,0,0);
        acc2b = __builtin_amdgcn_mfma_f32_16x16x32_f16(a2h, b2, acc2b, 0,0,0);
        acc2b = __builtin_amdgcn_mfma_f32_16x16x32_f16(a2l, b2, acc2b, 0,0,0);
        accO  = __builtin_amdgcn_mfma_f32_16x16x32_f16(a2h, b3, accO,  0,0,0);
      }
    }
    #pragma unroll
    for (int r = 0; r < 4; ++r) {
      int grow = rbase + r;
      g1s[grow*16 + n15] = acc1[r]  + prm[16 + n15];
      g2s[grow*16 + n15] = acc2a[r] + acc2b[r] + prm[32 + n15];
    }
    if (n15 == 0 && blk == ((t-1) & 255) && t >= 1 && t <= TS-1) {
      #pragma unroll
      for (int r = 0; r < 4; ++r)
        wt_store((u32*)&outp[(rbase+r)*TTS + (t-1)],
                 __builtin_bit_cast(u32, accO[r] + prm[48]));
    }
    __syncthreads();

    // ---- [E2(t)] c2,h2; stage hi|lo; AR partial dot ----
    {
      float gi = g2s[erow*16 + 0*4+eu];
      float gf = g2s[erow*16 + 1*4+eu];
      float gg = g2s[erow*16 + 2*4+eu];
      float go = g2s[erow*16 + 3*4+eu];
      c2 = sigm(gf)*c2 + sigm(gi)*tanhf(gg);
      float h2v = sigm(go)*tanhf(c2);
      f16 hh = (f16)h2v;
      sh2[erow*8 + eu]     = hh;
      sh2[erow*8 + 4 + eu] = (f16)(h2v - (float)hh);
      if (t >= TS-1) {
        float p = h2v * wlin_c;
        p += __shfl_xor(p, 1);
        p += __shfl_xor(p, 2);
        if (eu == 0)
          __hip_atomic_fetch_add(accs + (t-(TS-1))*BS + erow, p,
                                 __ATOMIC_RELAXED, __HIP_MEMORY_SCOPE_AGENT);
      }
    }
    if (t >= TS-1)   // drain each wave's acc adds before wv1's arrive2
      asm volatile("s_waitcnt vmcnt(0)" ::: "memory");
    __syncthreads();

    // ---- [wv1] store h2(t) (both halves) + arrive2 (wave-local ack) ----
    if (wv == 1) {
      st16_wt(H2 + (size_t)p1*P2STR + blk*1024 + lane*8,
              *(const f16x8*)(sh2 + lane*8));
      st16_wt(H2 + (size_t)p1*P2STR + blk*1024 + 512 + lane*8,
              *(const f16x8*)(sh2 + 512 + lane*8));
      asm volatile("s_waitcnt vmcnt(0)" ::: "memory");
      if (lane == 0)
        __hip_atomic_fetch_add(cnt2 + (blk & (NSLOT-1))*SLOT_STRIDE + (t+1), 1,
                               __ATOMIC_RELAXED, __HIP_MEMORY_SCOPE_AGENT);
    }
  }

  // ---- epilogue: out(TTS-1) from sums (writer block 63 = (TTS-1)&255) ----
  if (blk == 63) {
    if (wv == 7) poll_slots(cnt2, TTS);
    __syncthreads();
    if (tid < BS) {
      float v = __hip_atomic_load(accs + (TTS-TS)*BS + tid,
                                  __ATOMIC_RELAXED, __HIP_MEMORY_SCOPE_AGENT) + prm[48];
      wt_store((u32*)&outp[tid*TTS + (TTS-1)], __builtin_bit_cast(u32, v));
    }
  }
}

extern "C" void kernel_launch(void* const* d_in, const int* in_sizes, int n_in,
                              void* d_out, int out_size, void* d_ws, size_t ws_size,
                              hipStream_t stream) {
  const float* xg   = (const float*)d_in[0];
  const float* Wih1 = (const float*)d_in[1];
  const float* Whh1 = (const float*)d_in[2];
  const float* bih1 = (const float*)d_in[3];
  const float* bhh1 = (const float*)d_in[4];
  const float* Wih2 = (const float*)d_in[5];
  const float* Whh2 = (const float*)d_in[6];
  const float* bih2 = (const float*)d_in[7];
  const float* bhh2 = (const float*)d_in[8];
  const float* Wlin = (const float*)d_in[9];
  const float* blin = (const float*)d_in[10];
  float* outp = (float*)d_out;
  char* ws = (char*)d_ws;

  init_ws_kernel<<<dim3(128), dim3(256), 0, stream>>>(ws);

  (void)hipFuncSetAttribute((const void*)lstm_coop,
                            hipFuncAttributeMaxDynamicSharedMemorySize, LDS_TOTAL);

  void* args[] = { (void*)&xg, (void*)&Wih1, (void*)&Whh1, (void*)&bih1, (void*)&bhh1,
                   (void*)&Wih2, (void*)&Whh2, (void*)&bih2, (void*)&bhh2,
                   (void*)&Wlin, (void*)&blin, (void*)&outp, (void*)&ws };
  hipError_t err = hipLaunchCooperativeKernel((const void*)lstm_coop,
                                              dim3(NB), dim3(WGS), args, LDS_TOTAL, stream);
  if (err != hipSuccess) {
    lstm_coop<<<dim3(NB), dim3(WGS), LDS_TOTAL, stream>>>(
        xg, Wih1, Whh1, bih1, bhh1, Wih2, Whh2, bih2, bhh2, Wlin, blin, outp, ws);
  }
}

// Round 8
// 4689.779 us; speedup vs baseline: 1.5205x; 1.1822x over previous
//
#include <hip/hip_runtime.h>

// ============================================================================
// 2-layer LSTM (H=1024, B=128, T=256, future=64), persistent cooperative
// kernel, 256 WGs x 512 thr, 1 WG/CU, weights in LDS (MFMA B-frag order).
// R8: single-f16 h2 (lo-half dropped everywhere; evidence: TF outputs have
// been hi-only since R2 with absmax pinned at the bf16 floor). H2 layout ==
// H1 layout ([kblk][row][4], 1KB full-line store). k-loop: 4 dwordx2 loads +
// 4 MFMAs per k0; stream 512 KB/CU/step (-33%). Sync = R7's single-rendezvous
// XCD-leader scheme (wv0 stores h1+arrives, wv1 stores h2+arrives, wv7 polls,
// one leader fence per XCD per step). AR feedback stays f32-exact.
// ============================================================================

typedef _Float16 f16;
typedef _Float16 f16x8 __attribute__((ext_vector_type(8)));
typedef _Float16 f16x4 __attribute__((ext_vector_type(4)));
typedef float    f32x4 __attribute__((ext_vector_type(4)));
typedef int      i32x4 __attribute__((ext_vector_type(4)));
typedef unsigned int   u32;
typedef unsigned short u16;

#define NB   256
#define WGS  512
#define HS   1024
#define BS   128
#define TS   256
#define TTS  320
#define KST  32      // 1024 / 32
#define PSTR 131072  // f16 per plane: 256*128*4  (both H1 and H2)

// workspace byte offsets (layout kept from R5-R7; H2 slot now half-used)
#define OFF_H1    0u         // f16 [2][256][128][4]        524288 B
#define OFF_H2    524288u    // f16 [2][256][128][4]        262144 B used
#define OFF_CNT1  1572864u   // int [64 slots x 1024-int]   262144 B
#define OFF_CNT2  1835008u   // int [64 slots x 1024-int]   262144 B
#define OFF_FLAG  2097152u   // int [8 xcd x 2048-int]       65536 B
#define OFF_XREG  2162688u   // int [8 xcd x 16]               512 B
#define OFF_ACC   2163200u   // float [65][128]              33280 B
#define WS_END    2196480u

#define NSLOT       64
#define SLOT_TGT    4        // 256 blocks / 64 slots
#define SLOT_STRIDE 1024     // ints: 4KB between slots

// LDS byte offsets
#define LDS_G1    131072     // float[128][16]
#define LDS_G2    139264     // float[128][16]
#define LDS_XF    147456     // float[128]
#define LDS_PRM   147968     // wih1[16], b1[16], b2[16], blin
#define LDS_MISC  148224     // int[2]: xcd, leader
#define LDS_SH1   148352     // f16[512]  stage h1  [row][4]
#define LDS_SH2   149376     // f16[512]  stage h2  [row][4]
#define LDS_TOTAL 151552

__device__ __forceinline__ float sigm(float x){ return 1.0f/(1.0f + __expf(-x)); }

__device__ __forceinline__ void wt_store(u32* p, u32 v) {
  __hip_atomic_store(p, v, __ATOMIC_RELAXED, __HIP_MEMORY_SCOPE_AGENT);
}

// full-line write-through 16B store (to coherence point)
__device__ __forceinline__ void st16_wt(f16* addr, f16x8 v) {
  i32x4 d = __builtin_bit_cast(i32x4, v);
  asm volatile("global_store_dwordx4 %0, %1, off sc0 sc1"
               :: "v"(addr), "v"(d) : "memory");
}

// per-lane slot poll (call from wv7: lane l polls slot l)
__device__ __forceinline__ void poll_slots(const int* cnt, int t) {
  const int* p = cnt + (threadIdx.x & 63) * SLOT_STRIDE + t;
  while (__hip_atomic_load(p, __ATOMIC_RELAXED, __HIP_MEMORY_SCOPE_AGENT) < SLOT_TGT)
    __builtin_amdgcn_s_sleep(1);
}

__global__ void init_ws_kernel(char* ws){
  // zero cnt1 + cnt2 + flags + xreg + acc (contiguous)
  const size_t n = (WS_END - OFF_CNT1) / 16u;
  float4* r = (float4*)(ws + OFF_CNT1);
  float4 z = make_float4(0.f, 0.f, 0.f, 0.f);
  size_t stride = (size_t)gridDim.x * blockDim.x;
  for (size_t i = blockIdx.x*(size_t)blockDim.x + threadIdx.x; i < n; i += stride) r[i] = z;
  __builtin_amdgcn_fence(__ATOMIC_RELEASE, "agent");
}

__global__ void __launch_bounds__(WGS, 2)
lstm_coop(const float* __restrict__ xg,
          const float* __restrict__ Wih1, const float* __restrict__ Whh1,
          const float* __restrict__ bih1, const float* __restrict__ bhh1,
          const float* __restrict__ Wih2, const float* __restrict__ Whh2,
          const float* __restrict__ bih2, const float* __restrict__ bhh2,
          const float* __restrict__ Wlin, const float* __restrict__ blin,
          float* __restrict__ outp, char* __restrict__ ws)
{
  extern __shared__ char smem[];
  f16*   Wlds = (f16*)smem;                    // [(tile*32+k0)*64+lane]*8 f16
  float* g1s  = (float*)(smem + LDS_G1);
  float* g2s  = (float*)(smem + LDS_G2);
  float* xfd  = (float*)(smem + LDS_XF);
  float* prm  = (float*)(smem + LDS_PRM);
  int*   miscl= (int*)(smem + LDS_MISC);
  f16*   sh1  = (f16*)(smem + LDS_SH1);
  f16*   sh2  = (f16*)(smem + LDS_SH2);

  f16* H1  = (f16*)(ws + OFF_H1);
  f16* H2  = (f16*)(ws + OFF_H2);
  int* cnt1 = (int*)(ws + OFF_CNT1);
  int* cnt2 = (int*)(ws + OFF_CNT2);
  int* flags= (int*)(ws + OFF_FLAG);
  float* accs = (float*)(ws + OFF_ACC);

  const int tid = threadIdx.x;
  const int blk = blockIdx.x;

  // ---- XCD self-id + leader election (rank0 of each XCC_ID group) ----
  int xcd_raw;
  asm("s_getreg_b32 %0, hwreg(HW_REG_XCC_ID)" : "=s"(xcd_raw));
  if (tid == 0) {
    int x = xcd_raw & 7;
    int rank = __hip_atomic_fetch_add((int*)(ws + OFF_XREG) + x*16, 1,
                                      __ATOMIC_RELAXED, __HIP_MEMORY_SCOPE_AGENT);
    miscl[0] = x;
    miscl[1] = (rank == 0) ? 1 : 0;
  }

  // ---- prologue: pack weights into LDS in MFMA B-frag order ----
  // tiles: 0=G1(Whh1) 1=G2a(Wih2) 2=G2b(Whh2) 3=OUT(Wlin col0, rest 0)
  for (int item = tid; item < 4*KST*64; item += WGS) {
    int tile = item >> 11;
    int rem  = item & 2047;
    int k0   = rem >> 6;
    int lane = rem & 63;
    int n    = lane & 15;
    int kbase = k0*32 + (lane>>4)*8;
    f16x8 pk;
    if (tile < 3) {
      const float* Wsrc = (tile==0) ? Whh1 : (tile==1) ? Wih2 : Whh2;
      const float* p = Wsrc + (size_t)((n>>2)*1024 + blk*4 + (n&3))*HS + kbase;
      #pragma unroll
      for (int j=0;j<8;j++) pk[j] = (f16)p[j];
    } else {
      #pragma unroll
      for (int j=0;j<8;j++) pk[j] = (n==0) ? (f16)Wlin[kbase+j] : (f16)0.0f;
    }
    *(f16x8*)(Wlds + (size_t)item*8) = pk;
  }
  if (tid < 16) {
    int row = (tid>>2)*1024 + blk*4 + (tid&3);
    prm[tid]      = Wih1[row];
    prm[16 + tid] = bih1[row] + bhh1[row];
    prm[32 + tid] = bih2[row] + bhh2[row];
  }
  if (tid == 16) prm[48] = blin[0];

  const int erow = tid >> 2;        // elementwise: batch row
  const int eu   = tid & 3;         // unit within CU
  const float wlin_c = Wlin[blk*4 + eu];
  float c1 = 0.f, c2 = 0.f;
  __syncthreads();

  const int  myxcd  = miscl[0];
  const bool leader = miscl[1] != 0;
  int* flag = flags + myxcd * 2048;         // monotone t+1

  // MFMA identity
  const int wv    = tid >> 6;
  const int lane  = tid & 63;
  const int n15   = lane & 15;
  const int mrow  = wv*16 + n15;          // A-frag row (batch)
  const int kc    = (lane>>4)*8;          // A/B-frag k sub-offset
  const int rbase = wv*16 + (lane>>4)*4;  // C/D row base
  const f16x8* WB = (const f16x8*)Wlds;
  const int abase = mrow*4 + (kc>>2)*512; // frag base (f16), same for H1/H2

  for (int t = 0; t < TTS; ++t) {
    const int p1 = t & 1;          // h1(t)/h2(t) plane (written this step)
    const int p2 = (t + 1) & 1;    // h2(t-1) plane (read this step)

    // ---- [AR pre] out(t-1) from sums; fence-free (atomic loads) ----
    if (t >= TS) {
      if (wv == 7) poll_slots(cnt2, t);
      __syncthreads();
      if (tid < BS) {
        float v = __hip_atomic_load(accs + (t-TS)*BS + tid,
                                    __ATOMIC_RELAXED, __HIP_MEMORY_SCOPE_AGENT) + prm[48];
        xfd[tid] = v;
        if (blk == ((t-1) & 255))
          wt_store((u32*)&outp[tid*TTS + (t-1)], __builtin_bit_cast(u32, v));
      }
      __syncthreads();
    }

    // ---- [E1(t)] block-local: g1s(t-1) + x(t) (or xfd) ----
    {
      float h1v;
      if (t == 0) {
        float xv = xg[erow*TS + 0];
        float gi = xv*prm[0*4+eu] + prm[16 + 0*4+eu];
        float gg = xv*prm[2*4+eu] + prm[16 + 2*4+eu];
        float go = xv*prm[3*4+eu] + prm[16 + 3*4+eu];
        c1 = sigm(gi)*tanhf(gg);
        h1v = sigm(go)*tanhf(c1);
      } else {
        float xv = (t < TS) ? xg[erow*TS + t] : xfd[erow];
        float gi = g1s[erow*16 + 0*4+eu] + xv*prm[0*4+eu];
        float gf = g1s[erow*16 + 1*4+eu] + xv*prm[1*4+eu];
        float gg = g1s[erow*16 + 2*4+eu] + xv*prm[2*4+eu];
        float go = g1s[erow*16 + 3*4+eu] + xv*prm[3*4+eu];
        c1 = sigm(gf)*c1 + sigm(gi)*tanhf(gg);
        h1v = sigm(go)*tanhf(c1);
      }
      sh1[tid] = (f16)h1v;
    }
    __syncthreads();

    // ---- [wv0] store h1(t) + arrive1 (wave-local ack) ----
    if (wv == 0) {
      st16_wt(H1 + (size_t)p1*PSTR + blk*512 + lane*8,
              *(const f16x8*)(sh1 + lane*8));
      asm volatile("s_waitcnt vmcnt(0)" ::: "memory");
      if (lane == 0)
        __hip_atomic_fetch_add(cnt1 + (blk & (NSLOT-1))*SLOT_STRIDE + t, 1,
                               __ATOMIC_RELAXED, __HIP_MEMORY_SCOPE_AGENT);
    }

    // ---- [rendezvous] ONE leader fence per XCD gates h1(t)+h2(t-1) ----
    if (wv == 7) {
      if (leader) {
        if (t >= 1) poll_slots(cnt2, t);
        poll_slots(cnt1, t);
        __builtin_amdgcn_fence(__ATOMIC_ACQUIRE, "agent");   // one L1+L2 inv
        asm volatile("s_waitcnt vmcnt(0)" ::: "memory");
        if (lane == 0)
          __hip_atomic_store(flag, t + 1, __ATOMIC_RELAXED, __HIP_MEMORY_SCOPE_AGENT);
      } else {
        if (lane == 0) {
          while (__hip_atomic_load(flag, __ATOMIC_RELAXED, __HIP_MEMORY_SCOPE_AGENT) < t + 1)
            __builtin_amdgcn_s_sleep(1);
        }
      }
    }
    __syncthreads();

    // ---- [stream] fused h1+h2 k-loop: G1, G2a, G2b, accO (4 MFMAs/k0) ----
    const f16* A1 = H1 + (size_t)p1*PSTR + abase;
    const f16* A2 = H2 + (size_t)p2*PSTR + abase;
    f32x4 acc1  = {0.f,0.f,0.f,0.f};
    f32x4 acc2a = {0.f,0.f,0.f,0.f};
    f32x4 acc2b = {0.f,0.f,0.f,0.f};
    f32x4 accO  = {0.f,0.f,0.f,0.f};
    if (t == 0) {   // h2(-1) == 0: h1-only
      #pragma unroll 8
      for (int k0 = 0; k0 < KST; ++k0) {
        f16x4 a1l = *(const f16x4*)(A1 + k0*4096);
        f16x4 a1h = *(const f16x4*)(A1 + k0*4096 + 512);
        f16x8 a1  = __builtin_shufflevector(a1l, a1h, 0,1,2,3,4,5,6,7);
        f16x8 b0 = WB[(0*KST + k0)*64 + lane];
        f16x8 b1 = WB[(1*KST + k0)*64 + lane];
        acc1  = __builtin_amdgcn_mfma_f32_16x16x32_f16(a1, b0, acc1,  0,0,0);
        acc2a = __builtin_amdgcn_mfma_f32_16x16x32_f16(a1, b1, acc2a, 0,0,0);
      }
    } else {
      #pragma unroll 8
      for (int k0 = 0; k0 < KST; ++k0) {
        f16x4 a1l = *(const f16x4*)(A1 + k0*4096);
        f16x4 a1h = *(const f16x4*)(A1 + k0*4096 + 512);
        f16x4 a2l = *(const f16x4*)(A2 + k0*4096);
        f16x4 a2h = *(const f16x4*)(A2 + k0*4096 + 512);
        f16x8 a1  = __builtin_shufflevector(a1l, a1h, 0,1,2,3,4,5,6,7);
        f16x8 a2  = __builtin_shufflevector(a2l, a2h, 0,1,2,3,4,5,6,7);
        f16x8 b0 = WB[(0*KST + k0)*64 + lane];
        f16x8 b1 = WB[(1*KST + k0)*64 + lane];
        f16x8 b2 = WB[(2*KST + k0)*64 + lane];
        f16x8 b3 = WB[(3*KST + k0)*64 + lane];
        acc1  = __builtin_amdgcn_mfma_f32_16x16x32_f16(a1, b0, acc1,  0,0,0);
        acc2a = __builtin_amdgcn_mfma_f32_16x16x32_f16(a1, b1, acc2a, 0,0,0);
        acc2b = __builtin_amdgcn_mfma_f32_16x16x32_f16(a2, b2, acc2b, 0,0,0);
        accO  = __builtin_amdgcn_mfma_f32_16x16x32_f16(a2, b3, accO,  0,0,0);
      }
    }
    #pragma unroll
    for (int r = 0; r < 4; ++r) {
      int grow = rbase + r;
      g1s[grow*16 + n15] = acc1[r]  + prm[16 + n15];
      g2s[grow*16 + n15] = acc2a[r] + acc2b[r] + prm[32 + n15];
    }
    if (n15 == 0 && blk == ((t-1) & 255) && t >= 1 && t <= TS-1) {
      #pragma unroll
      for (int r = 0; r < 4; ++r)
        wt_store((u32*)&outp[(rbase+r)*TTS + (t-1)],
                 __builtin_bit_cast(u32, accO[r] + prm[48]));
    }
    __syncthreads();

    // ---- [E2(t)] c2,h2; stage; AR partial dot ----
    {
      float gi = g2s[erow*16 + 0*4+eu];
      float gf = g2s[erow*16 + 1*4+eu];
      float gg = g2s[erow*16 + 2*4+eu];
      float go = g2s[erow*16 + 3*4+eu];
      c2 = sigm(gf)*c2 + sigm(gi)*tanhf(gg);
      float h2v = sigm(go)*tanhf(c2);
      sh2[tid] = (f16)h2v;
      if (t >= TS-1) {
        float p = h2v * wlin_c;
        p += __shfl_xor(p, 1);
        p += __shfl_xor(p, 2);
        if (eu == 0)
          __hip_atomic_fetch_add(accs + (t-(TS-1))*BS + erow, p,
                                 __ATOMIC_RELAXED, __HIP_MEMORY_SCOPE_AGENT);
      }
    }
    if (t >= TS-1)   // drain each wave's acc adds before wv1's arrive2
      asm volatile("s_waitcnt vmcnt(0)" ::: "memory");
    __syncthreads();

    // ---- [wv1] store h2(t) + arrive2 (wave-local ack) ----
    if (wv == 1) {
      st16_wt(H2 + (size_t)p1*PSTR + blk*512 + lane*8,
              *(const f16x8*)(sh2 + lane*8));
      asm volatile("s_waitcnt vmcnt(0)" ::: "memory");
      if (lane == 0)
        __hip_atomic_fetch_add(cnt2 + (blk & (NSLOT-1))*SLOT_STRIDE + (t+1), 1,
                               __ATOMIC_RELAXED, __HIP_MEMORY_SCOPE_AGENT);
    }
  }

  // ---- epilogue: out(TTS-1) from sums (writer block 63 = (TTS-1)&255) ----
  if (blk == 63) {
    if (wv == 7) poll_slots(cnt2, TTS);
    __syncthreads();
    if (tid < BS) {
      float v = __hip_atomic_load(accs + (TTS-TS)*BS + tid,
                                  __ATOMIC_RELAXED, __HIP_MEMORY_SCOPE_AGENT) + prm[48];
      wt_store((u32*)&outp[tid*TTS + (TTS-1)], __builtin_bit_cast(u32, v));
    }
  }
}

extern "C" void kernel_launch(void* const* d_in, const int* in_sizes, int n_in,
                              void* d_out, int out_size, void* d_ws, size_t ws_size,
                              hipStream_t stream) {
  const float* xg   = (const float*)d_in[0];
  const float* Wih1 = (const float*)d_in[1];
  const float* Whh1 = (const float*)d_in[2];
  const float* bih1 = (const float*)d_in[3];
  const float* bhh1 = (const float*)d_in[4];
  const float* Wih2 = (const float*)d_in[5];
  const float* Whh2 = (const float*)d_in[6];
  const float* bih2 = (const float*)d_in[7];
  const float* bhh2 = (const float*)d_in[8];
  const float* Wlin = (const float*)d_in[9];
  const float* blin = (const float*)d_in[10];
  float* outp = (float*)d_out;
  char* ws = (char*)d_ws;

  init_ws_kernel<<<dim3(128), dim3(256), 0, stream>>>(ws);

  (void)hipFuncSetAttribute((const void*)lstm_coop,
                            hipFuncAttributeMaxDynamicSharedMemorySize, LDS_TOTAL);

  void* args[] = { (void*)&xg, (void*)&Wih1, (void*)&Whh1, (void*)&bih1, (void*)&bhh1,
                   (void*)&Wih2, (void*)&Whh2, (void*)&bih2, (void*)&bhh2,
                   (void*)&Wlin, (void*)&blin, (void*)&outp, (void*)&ws };
  hipError_t err = hipLaunchCooperativeKernel((const void*)lstm_coop,
                                              dim3(NB), dim3(WGS), args, LDS_TOTAL, stream);
  if (err != hipSuccess) {
    lstm_coop<<<dim3(NB), dim3(WGS), LDS_TOTAL, stream>>>(
        xg, Wih1, Whh1, bih1, bhh1, Wih2, Whh2, bih2, bhh2, Wlin, blin, outp, ws);
  }
}